// Round 5
// baseline (644.460 us; speedup 1.0000x reference)
//
#include <hip/hip_runtime.h>

// GraphNormalization on MI355X — phase-overlapped segment pipeline.
//
// Evidence so far: traffic is minimal (FETCH 1.03 GB, WRITE 1.03 GB; pass-B
// re-read 100% cache-absorbed), but lockstep blocks serialize a read-only
// phase (~3.2 TB/s read ceiling) then a write phase. Reads and writes
// overlap independently at the HBM (copy: 3.15R+3.15W; fill: 6.4W).
// R5: 512 blocks x 4 segments each (2 node + 2 edge). After finalizing
// stats of task t, one interleaved loop writes task t (L2 re-read + HBM
// store) WHILE streaming the stats-read of task t+1 (HBM), pipelined one
// load ahead so an HBM read is always in flight. 3/4 of reads overlap
// writes -> model ~378 us vs measured 588.

static constexpr int   D4  = 32;     // D/4, D = 128 fixed by problem
static constexpr float EPS = 1e-5f;

typedef float vfloat4 __attribute__((ext_vector_type(4)));

__device__ __forceinline__ void nt_store4(float4* p, const float4& v) {
    vfloat4 w = { v.x, v.y, v.z, v.w };
    __builtin_nontemporal_store(w, reinterpret_cast<vfloat4*>(p));
}

__device__ __forceinline__ void acc4(float4& s, float4& q, const float4& v) {
    s.x += v.x; s.y += v.y; s.z += v.z; s.w += v.w;
    q.x += v.x * v.x; q.y += v.y * v.y;
    q.z += v.z * v.z; q.w += v.w * v.w;
}

// Block k handles tasks: 0 = node seg 2k, 1 = node seg 2k+1,
//                        2 = edge seg 2k, 3 = edge seg 2k+1.
__global__ __launch_bounds__(256) void seg_norm_pipe(
    const float4* __restrict__ xn, const float4* __restrict__ xe,
    const float*  __restrict__ gn, const float*  __restrict__ bn,
    const float*  __restrict__ ge, const float*  __restrict__ be,
    const int*    __restrict__ sn, const int*    __restrict__ se,
    float4* __restrict__ on, float4* __restrict__ oe,
    int N)
{
    const int k    = (int)blockIdx.x;
    const int tid  = (int)threadIdx.x;
    const int lane = tid & 31;   // dim-group: 4 dims per lane
    const int rg   = tid >> 5;   // row-group 0..7

    __shared__ int    sb[8];                 // [2t]=start, [2t+1]=end of task t
    __shared__ float4 redS[256], redQ[256];
    __shared__ float4 sA[32], sBc[32];

    if (tid < 8) {
        const int t      = tid >> 1;
        const int* sg    = (t < 2) ? sn : se;
        const int target = 2 * k + (t & 1) + (tid & 1);
        int lo = 0, hi = N;
        while (lo < hi) {
            int mid = (lo + hi) >> 1;
            if (sg[mid] < target) lo = mid + 1; else hi = mid;
        }
        sb[tid] = lo;
    }
    __syncthreads();

    float4 s = make_float4(0.f, 0.f, 0.f, 0.f);
    float4 q = make_float4(0.f, 0.f, 0.f, 0.f);

    // --- prologue: stats of task 0 (pure HBM read) ---
    {
        const int st = sb[0], en = sb[1];
        for (int r = st + rg; r < en; r += 8)
            acc4(s, q, xn[(size_t)r * D4 + lane]);
    }

    #pragma unroll 4
    for (int t = 0; t < 4; ++t) {
        const float4* __restrict__ xp = (t < 2) ? xn : xe;
        float4*       __restrict__ op = (t < 2) ? on : oe;
        const float*  __restrict__ gm = (t < 2) ? gn : ge;
        const float*  __restrict__ bt = (t < 2) ? bn : be;
        const int stp = sb[2 * t], enp = sb[2 * t + 1];
        const int cnt = enp - stp;

        // --- finalize stats of task t -> per-lane scale A / bias Bc ---
        __syncthreads();                 // prior sA/sBc consumers hold regs
        redS[tid] = s; redQ[tid] = q;
        __syncthreads();
        if (tid < 32) {
            float4 S = redS[tid], Q = redQ[tid];
            #pragma unroll
            for (int j = 1; j < 8; ++j) {
                const float4 a = redS[j * 32 + tid];
                const float4 c = redQ[j * 32 + tid];
                S.x += a.x; S.y += a.y; S.z += a.z; S.w += a.w;
                Q.x += c.x; Q.y += c.y; Q.z += c.z; Q.w += c.w;
            }
            const float rcnt = 1.0f / (float)max(cnt, 1);
            float4 m, iv;
            m.x = S.x * rcnt; m.y = S.y * rcnt; m.z = S.z * rcnt; m.w = S.w * rcnt;
            const float vx = fmaxf(Q.x * rcnt - m.x * m.x, 0.f);
            const float vy = fmaxf(Q.y * rcnt - m.y * m.y, 0.f);
            const float vz = fmaxf(Q.z * rcnt - m.z * m.z, 0.f);
            const float vw = fmaxf(Q.w * rcnt - m.w * m.w, 0.f);
            iv.x = 1.0f / (sqrtf(vx) + EPS);
            iv.y = 1.0f / (sqrtf(vy) + EPS);
            iv.z = 1.0f / (sqrtf(vz) + EPS);
            iv.w = 1.0f / (sqrtf(vw) + EPS);
            if (cnt <= 1) {              // pass-through: out = x*gamma + beta
                m.x = m.y = m.z = m.w = 0.f;
                iv.x = iv.y = iv.z = iv.w = 1.f;
            }
            const float4 g4 = ((const float4*)gm)[tid];
            const float4 b4 = ((const float4*)bt)[tid];
            float4 A, Bc;
            A.x = iv.x * g4.x; A.y = iv.y * g4.y;
            A.z = iv.z * g4.z; A.w = iv.w * g4.w;
            Bc.x = b4.x - m.x * A.x; Bc.y = b4.y - m.y * A.y;
            Bc.z = b4.z - m.z * A.z; Bc.w = b4.w - m.w * A.w;
            sA[tid] = A; sBc[tid] = Bc;
        }
        __syncthreads();
        const float4 A  = sA[lane];
        const float4 Bc = sBc[lane];

        // --- next-task stats stream (empty for t == 3) ---
        int stc = 0, enc = 0;
        const float4* __restrict__ xc = xn;
        if (t < 3) {
            xc  = (t == 0) ? xn : xe;    // task1=node, task2/3=edge
            stc = sb[2 * t + 2];
            enc = sb[2 * t + 3];
        }

        s = make_float4(0.f, 0.f, 0.f, 0.f);
        q = make_float4(0.f, 0.f, 0.f, 0.f);

        // --- interleaved: write task t (L2 re-read + HBM store) while
        //     streaming stats-read of task t+1 (HBM), one load ahead. ---
        int rp  = stp + rg;              // prev-task row (write stream)
        int rcl = stc + rg;              // next cur-task row to load
        float4 vc = make_float4(0.f, 0.f, 0.f, 0.f);
        bool pend = false;               // vc holds a loaded, unconsumed row
        if (rcl < enc) { vc = xc[(size_t)rcl * D4 + lane]; pend = true; rcl += 8; }
        while (rp < enp || pend) {
            // issue order: vp (L2 hit), vc2 (HBM) -> consuming vp waits
            // vmcnt(1), leaving the HBM read in flight.
            float4 vp; const bool hp = (rp < enp);
            if (hp) vp = xp[(size_t)rp * D4 + lane];
            float4 vc2 = make_float4(0.f, 0.f, 0.f, 0.f);
            bool pend2 = false;
            if (rcl < enc) { vc2 = xc[(size_t)rcl * D4 + lane]; pend2 = true; rcl += 8; }
            if (hp) {
                float4 o;
                o.x = vp.x * A.x + Bc.x; o.y = vp.y * A.y + Bc.y;
                o.z = vp.z * A.z + Bc.z; o.w = vp.w * A.w + Bc.w;
                nt_store4(&op[(size_t)rp * D4 + lane], o);
                rp += 8;
            }
            if (pend) acc4(s, q, vc);
            vc = vc2; pend = pend2;
        }
    }
}

extern "C" void kernel_launch(void* const* d_in, const int* in_sizes, int n_in,
                              void* d_out, int out_size, void* d_ws, size_t ws_size,
                              hipStream_t stream) {
    const float* node_feat  = (const float*)d_in[0];
    const float* edge_feat  = (const float*)d_in[1];
    const float* node_gamma = (const float*)d_in[2];
    const float* node_beta  = (const float*)d_in[3];
    const float* edge_gamma = (const float*)d_in[4];
    const float* edge_beta  = (const float*)d_in[5];
    const int*   node_seg   = (const int*)d_in[6];
    const int*   edge_seg   = (const int*)d_in[7];

    const int D = in_sizes[2];        // 128
    const int N = in_sizes[0] / D;    // 1,000,000
    const int B = 1024;               // num_graphs (fixed by setup_inputs)

    float* out_node = (float*)d_out;
    float* out_edge = out_node + (size_t)N * (size_t)D;

    dim3 grid((unsigned)(B / 2));     // 512 blocks, 4 segments each
    seg_norm_pipe<<<grid, 256, 0, stream>>>(
        (const float4*)node_feat, (const float4*)edge_feat,
        node_gamma, node_beta, edge_gamma, edge_beta,
        node_seg, edge_seg,
        (float4*)out_node, (float4*)out_edge, N);
}

// Round 6
// 569.089 us; speedup vs baseline: 1.1324x; 1.1324x over previous
//
#include <hip/hip_runtime.h>

// GraphNormalization on MI355X — async global_load_lds streaming pipeline.
//
// Model fitting R0-R5: every VGPR-load variant holds ~1 outstanding 1KB
// load/wave (regalloc re-serializes; VGPR_Count 24-36 proves it), giving
// 16-32KB/CU in flight -> 3.0-3.3 TB/s at ~1.2us loaded latency, invariant
// to occupancy (R0 76% vs R5 23%: same BW). Fix: global_load_lds staging
// (no VGPR payload, counted vmcnt double-buffer) -> 64KB/CU in flight.
//
// One 256-thread block per (segment,tensor); wave-private 2x4KB LDS tiles;
// pass A: stage->acc sum/sumsq; pass B: stage (L3-hit re-read) -> fma ->
// NT store. Tails via plain loads. Traffic stays 1.03GB R + 1.03GB W.

static constexpr int   D4     = 32;    // D/4, D = 128
static constexpr int   CHUNK  = 64;    // float4 per staging inst (1KB/wave)
static constexpr int   NCHUNK = 4;     // insts per wave-tile
static constexpr int   TILE_W = CHUNK * NCHUNK;  // 256 f4 = 4KB per wave
static constexpr int   TILE_B = TILE_W * 4;      // 1024 f4 per block-tile
static constexpr float EPS    = 1e-5f;

typedef float vfloat4 __attribute__((ext_vector_type(4)));

#define WAITV(N) do { asm volatile("s_waitcnt vmcnt(" #N ")" ::: "memory"); \
                      __builtin_amdgcn_sched_barrier(0); } while (0)

__device__ __forceinline__ void nt_store4(float4* p, const float4& v) {
    vfloat4 w = { v.x, v.y, v.z, v.w };
    __builtin_nontemporal_store(w, reinterpret_cast<vfloat4*>(p));
}

__device__ __forceinline__ void acc4(float4& s, float4& q, const float4& v) {
    s.x += v.x; s.y += v.y; s.z += v.z; s.w += v.w;
    q.x += v.x * v.x; q.y += v.y * v.y;
    q.z += v.z * v.z; q.w += v.w * v.w;
}

__global__ __launch_bounds__(256) void seg_norm_async(
    const float4* __restrict__ xn, const float4* __restrict__ xe,
    const float*  __restrict__ gn, const float*  __restrict__ bn,
    const float*  __restrict__ ge, const float*  __restrict__ be,
    const int*    __restrict__ sn, const int*    __restrict__ se,
    float4* __restrict__ on, float4* __restrict__ oe,
    int N)
{
    __shared__ float4 stage[4][2][TILE_W];      // 32 KB, wave-private pairs
    __shared__ float4 redS[256], redQ[256];     // 8 KB
    __shared__ int    s_bounds[2];

    const bool is_edge = (blockIdx.y != 0);
    const float4* __restrict__ x   = is_edge ? xe : xn;
    const float*  __restrict__ gam = is_edge ? ge : gn;
    const float*  __restrict__ bet = is_edge ? be : bn;
    const int*    __restrict__ seg = is_edge ? se : sn;
    float4*       __restrict__ out = is_edge ? oe : on;

    const int b   = (int)blockIdx.x;
    const int tid = (int)threadIdx.x;

    if (tid < 2) {
        const int target = b + tid;
        int lo = 0, hi = N;
        while (lo < hi) {
            int mid = (lo + hi) >> 1;
            if (seg[mid] < target) lo = mid + 1; else hi = mid;
        }
        s_bounds[tid] = lo;
    }
    __syncthreads();
    const int start = s_bounds[0];
    const int end   = s_bounds[1];
    const int cnt   = end - start;
    if (cnt <= 0) return;

    const int w    = tid >> 6;    // wave 0..3
    const int lane = tid & 63;
    const int dg   = tid & 31;    // dim-group (float4 flat idx mod 32 == lane&31)

    const size_t f4base = (size_t)start * D4;
    const int    f4cnt  = cnt * D4;
    const int    nt     = f4cnt / TILE_B;

    float4* const sb0 = &stage[w][0][0];
    float4* const sb1 = &stage[w][1][0];

    // stage one 4KB wave-tile: 4 async 1KB loads, LDS base wave-uniform
    auto issue = [&](int t, float4* lp) {
        const float4* gp = x + f4base + (size_t)t * TILE_B + w * TILE_W + lane;
        #pragma unroll
        for (int i = 0; i < NCHUNK; ++i)
            __builtin_amdgcn_global_load_lds(gp + i * CHUNK, lp + i * CHUNK, 16, 0, 0);
    };

    // --- pass A: stats via async-staged stream ---
    float4 s = make_float4(0.f, 0.f, 0.f, 0.f);
    float4 q = make_float4(0.f, 0.f, 0.f, 0.f);
    if (nt > 0) {
        issue(0, sb0);
        for (int t = 0; t < nt; ++t) {
            float4* cur = (t & 1) ? sb1 : sb0;
            float4* nxt = (t & 1) ? sb0 : sb1;
            if (t + 1 < nt) { issue(t + 1, nxt); WAITV(4); }
            else            { WAITV(0); }
            #pragma unroll
            for (int i = 0; i < NCHUNK; ++i)
                acc4(s, q, cur[i * CHUNK + lane]);
        }
    }
    for (int j = nt * TILE_B + tid; j < f4cnt; j += 256)
        acc4(s, q, x[f4base + j]);

    redS[tid] = s; redQ[tid] = q;
    __syncthreads();

    // --- reduce 8 partials per dim-group; fold gamma/beta/mean/rstd ---
    if (tid < 32) {
        float4 S = redS[tid], Q = redQ[tid];
        #pragma unroll
        for (int k = 1; k < 8; ++k) {
            const float4 a = redS[k * 32 + tid];
            const float4 c = redQ[k * 32 + tid];
            S.x += a.x; S.y += a.y; S.z += a.z; S.w += a.w;
            Q.x += c.x; Q.y += c.y; Q.z += c.z; Q.w += c.w;
        }
        const float rc = 1.0f / (float)cnt;
        float4 m, iv;
        m.x = S.x * rc; m.y = S.y * rc; m.z = S.z * rc; m.w = S.w * rc;
        const float vx = fmaxf(Q.x * rc - m.x * m.x, 0.f);
        const float vy = fmaxf(Q.y * rc - m.y * m.y, 0.f);
        const float vz = fmaxf(Q.z * rc - m.z * m.z, 0.f);
        const float vw = fmaxf(Q.w * rc - m.w * m.w, 0.f);
        iv.x = 1.0f / (sqrtf(vx) + EPS);
        iv.y = 1.0f / (sqrtf(vy) + EPS);
        iv.z = 1.0f / (sqrtf(vz) + EPS);
        iv.w = 1.0f / (sqrtf(vw) + EPS);
        if (cnt <= 1) {  // pass-through: out = x*gamma + beta
            m.x = m.y = m.z = m.w = 0.f;
            iv.x = iv.y = iv.z = iv.w = 1.f;
        }
        const float4 g4 = ((const float4*)gam)[tid];
        const float4 b4 = ((const float4*)bet)[tid];
        float4 A, Bc;
        A.x = iv.x * g4.x; A.y = iv.y * g4.y;
        A.z = iv.z * g4.z; A.w = iv.w * g4.w;
        Bc.x = b4.x - m.x * A.x; Bc.y = b4.y - m.y * A.y;
        Bc.z = b4.z - m.z * A.z; Bc.w = b4.w - m.w * A.w;
        redS[tid] = A; redQ[tid] = Bc;   // same-wave lanes only
    }
    __syncthreads();
    const float4 A  = redS[dg];
    const float4 Bc = redQ[dg];
    __syncthreads();   // everyone has A/Bc before stage[] is overwritten

    // --- pass B: async-staged re-read (L2/L3 hit) -> fma -> NT store ---
    if (nt > 0) {
        issue(0, sb0);
        for (int t = 0; t < nt; ++t) {
            float4* cur = (t & 1) ? sb1 : sb0;
            float4* nxt = (t & 1) ? sb0 : sb1;
            const bool hn = (t + 1 < nt);
            if (hn) issue(t + 1, nxt);
            // in-order vmcnt retirement: count newer ops between wait and
            // the tile-t loads: hn -> 4 loads, t>0 -> 4 stores from t-1.
            if (t == 0) { if (hn) WAITV(4); else WAITV(0); }
            else        { if (hn) WAITV(8); else WAITV(4); }
            float4* op = out + f4base + (size_t)t * TILE_B + w * TILE_W + lane;
            #pragma unroll
            for (int i = 0; i < NCHUNK; ++i) {
                const float4 v = cur[i * CHUNK + lane];
                float4 o;
                o.x = v.x * A.x + Bc.x; o.y = v.y * A.y + Bc.y;
                o.z = v.z * A.z + Bc.z; o.w = v.w * A.w + Bc.w;
                nt_store4(op + i * CHUNK, o);
            }
        }
    }
    for (int j = nt * TILE_B + tid; j < f4cnt; j += 256) {
        const float4 v = x[f4base + j];
        float4 o;
        o.x = v.x * A.x + Bc.x; o.y = v.y * A.y + Bc.y;
        o.z = v.z * A.z + Bc.z; o.w = v.w * A.w + Bc.w;
        nt_store4(&((float4*)out)[f4base + j], o);
    }
}

extern "C" void kernel_launch(void* const* d_in, const int* in_sizes, int n_in,
                              void* d_out, int out_size, void* d_ws, size_t ws_size,
                              hipStream_t stream) {
    const float* node_feat  = (const float*)d_in[0];
    const float* edge_feat  = (const float*)d_in[1];
    const float* node_gamma = (const float*)d_in[2];
    const float* node_beta  = (const float*)d_in[3];
    const float* edge_gamma = (const float*)d_in[4];
    const float* edge_beta  = (const float*)d_in[5];
    const int*   node_seg   = (const int*)d_in[6];
    const int*   edge_seg   = (const int*)d_in[7];

    const int D = in_sizes[2];        // 128
    const int N = in_sizes[0] / D;    // 1,000,000
    const int B = 1024;               // num_graphs (fixed by setup_inputs)

    float* out_node = (float*)d_out;
    float* out_edge = out_node + (size_t)N * (size_t)D;

    dim3 grid((unsigned)B, 2);
    seg_norm_async<<<grid, 256, 0, stream>>>(
        (const float4*)node_feat, (const float4*)edge_feat,
        node_gamma, node_beta, edge_gamma, edge_beta,
        node_seg, edge_seg,
        (float4*)out_node, (float4*)out_edge, N);
}

// Round 7
// 555.910 us; speedup vs baseline: 1.1593x; 1.0237x over previous
//
#include <hip/hip_runtime.h>

// GraphNormalization on MI355X — R7: cross-task read/write overlap.
//
// Established (R0-R6): traffic is minimal (FETCH 1.03GB, WRITE 1.03GB; the
// per-segment re-read is fully cache-absorbed); read-dominant phases pin at
// ~3.3 TB/s regardless of occupancy (23-76%) or per-wave MLP (1-4KB async);
// writes alone reach 6.4 TB/s; copy = 3.15R+3.15W concurrently. The loss is
// structural: pass A (pure read) and pass B (write-paced) never overlap.
//
// R7: one block per graph id b, two tasks (node seg b, edge seg b).
//   P1: async-stage node -> stats.           [HBM read]
//   P2: FUSED: write node (staged L2/L3 re-read + NT store)
//             || stats-read edge (staged HBM read), counted vmcnt.
//   P3: write edge (staged L2/L3 re-read + NT store).
// Chip-wide: P2's writes hide under P2's reads -> read-paced total.

static constexpr int   D4     = 32;              // D/4, D = 128
static constexpr int   CHUNK  = 64;              // f4 per staging inst (1KB/wave)
static constexpr int   NCHUNK = 4;               // insts per wave-tile
static constexpr int   TILE_W = CHUNK * NCHUNK;  // 256 f4 = 4KB per wave
static constexpr int   TILE_B = TILE_W * 4;      // 1024 f4 per block-tile
static constexpr float EPS    = 1e-5f;

typedef float vfloat4 __attribute__((ext_vector_type(4)));

#define WAITV(N) do { asm volatile("s_waitcnt vmcnt(" #N ")" ::: "memory"); \
                      __builtin_amdgcn_sched_barrier(0); } while (0)

__device__ __forceinline__ void nt_store4(float4* p, const float4& v) {
    vfloat4 w = { v.x, v.y, v.z, v.w };
    __builtin_nontemporal_store(w, reinterpret_cast<vfloat4*>(p));
}

__device__ __forceinline__ void acc4(float4& s, float4& q, const float4& v) {
    s.x += v.x; s.y += v.y; s.z += v.z; s.w += v.w;
    q.x += v.x * v.x; q.y += v.y * v.y;
    q.z += v.z * v.z; q.w += v.w * v.w;
}

__device__ __forceinline__ float4 affine4(const float4& v, const float4& A,
                                          const float4& Bc) {
    float4 o;
    o.x = v.x * A.x + Bc.x; o.y = v.y * A.y + Bc.y;
    o.z = v.z * A.z + Bc.z; o.w = v.w * A.w + Bc.w;
    return o;
}

__global__ __launch_bounds__(256) void seg_norm_fused(
    const float4* __restrict__ xn, const float4* __restrict__ xe,
    const float*  __restrict__ gn, const float*  __restrict__ bn,
    const float*  __restrict__ ge, const float*  __restrict__ be,
    const int*    __restrict__ sn, const int*    __restrict__ se,
    float4* __restrict__ on, float4* __restrict__ oe,
    int N)
{
    __shared__ float4 stage[4][2][2][TILE_W];   // [wave][stream][buf] 64KB
    __shared__ float4 redS[256], redQ[256];     // 8KB
    __shared__ int    sb[4];                    // nodeStart,nodeEnd,edgeStart,edgeEnd

    const int b    = (int)blockIdx.x;
    const int tid  = (int)threadIdx.x;
    const int w    = tid >> 6;
    const int lane = tid & 63;
    const int dg   = tid & 31;

    if (tid < 4) {
        const int* sg    = (tid < 2) ? sn : se;
        const int target = b + (tid & 1);
        int lo = 0, hi = N;
        while (lo < hi) {
            int mid = (lo + hi) >> 1;
            if (sg[mid] < target) lo = mid + 1; else hi = mid;
        }
        sb[tid] = lo;
    }
    __syncthreads();
    const int    stN = sb[0], cntN = sb[1] - sb[0];
    const int    stE = sb[2], cntE = sb[3] - sb[2];
    const size_t fbN = (size_t)stN * D4;  const int fcN = cntN * D4;
    const size_t fbE = (size_t)stE * D4;  const int fcE = cntE * D4;
    const int    ntN = fcN / TILE_B,      ntE = fcE / TILE_B;
    const int    tmid = min(ntN, ntE);

    float4* const nb0 = &stage[w][0][0][0];
    float4* const nb1 = &stage[w][0][1][0];
    float4* const eb0 = &stage[w][1][0][0];
    float4* const eb1 = &stage[w][1][1][0];

    auto issue = [&](const float4* src, size_t fb, int t, float4* lp) {
        const float4* gp = src + fb + (size_t)t * TILE_B + w * TILE_W + lane;
        #pragma unroll
        for (int i = 0; i < NCHUNK; ++i)
            __builtin_amdgcn_global_load_lds(gp + i * CHUNK, lp + i * CHUNK, 16, 0, 0);
    };

    // ---------------- P1: node stats (HBM read, double-buffered) ----------
    float4 s = make_float4(0.f, 0.f, 0.f, 0.f);
    float4 q = make_float4(0.f, 0.f, 0.f, 0.f);
    if (ntN > 0) {
        issue(xn, fbN, 0, nb0);
        for (int t = 0; t < ntN; ++t) {
            float4* cur = (t & 1) ? nb1 : nb0;
            float4* nxt = (t & 1) ? nb0 : nb1;
            if (t + 1 < ntN) { issue(xn, fbN, t + 1, nxt); WAITV(4); }
            else             { WAITV(0); }
            #pragma unroll
            for (int i = 0; i < NCHUNK; ++i)
                acc4(s, q, cur[i * CHUNK + lane]);
        }
    }
    for (int j = ntN * TILE_B + tid; j < fcN; j += 256)
        acc4(s, q, xn[fbN + j]);

    // ---------------- reduce -> A0/Bc0 (node) -----------------------------
    redS[tid] = s; redQ[tid] = q;
    __syncthreads();
    if (tid < 32) {
        float4 S = redS[tid], Q = redQ[tid];
        #pragma unroll
        for (int k = 1; k < 8; ++k) {
            const float4 a = redS[k * 32 + tid], c = redQ[k * 32 + tid];
            S.x += a.x; S.y += a.y; S.z += a.z; S.w += a.w;
            Q.x += c.x; Q.y += c.y; Q.z += c.z; Q.w += c.w;
        }
        const float rc = 1.0f / (float)max(cntN, 1);
        float4 m, iv;
        m.x = S.x * rc; m.y = S.y * rc; m.z = S.z * rc; m.w = S.w * rc;
        iv.x = 1.0f / (sqrtf(fmaxf(Q.x * rc - m.x * m.x, 0.f)) + EPS);
        iv.y = 1.0f / (sqrtf(fmaxf(Q.y * rc - m.y * m.y, 0.f)) + EPS);
        iv.z = 1.0f / (sqrtf(fmaxf(Q.z * rc - m.z * m.z, 0.f)) + EPS);
        iv.w = 1.0f / (sqrtf(fmaxf(Q.w * rc - m.w * m.w, 0.f)) + EPS);
        if (cntN <= 1) { m = make_float4(0,0,0,0); iv = make_float4(1,1,1,1); }
        const float4 g4 = ((const float4*)gn)[tid];
        const float4 b4 = ((const float4*)bn)[tid];
        float4 A, Bc;
        A.x = iv.x * g4.x; A.y = iv.y * g4.y; A.z = iv.z * g4.z; A.w = iv.w * g4.w;
        Bc.x = b4.x - m.x * A.x; Bc.y = b4.y - m.y * A.y;
        Bc.z = b4.z - m.z * A.z; Bc.w = b4.w - m.w * A.w;
        redS[tid] = A; redQ[tid] = Bc;      // same-wave only: safe
    }
    __syncthreads();
    const float4 A0  = redS[dg];
    const float4 Bc0 = redQ[dg];
    __syncthreads();                         // all have A0 before redS reuse

    // ------- P2: FUSED  node write (L2/L3 staged) || edge stats (HBM) -----
    s = make_float4(0.f, 0.f, 0.f, 0.f);
    q = make_float4(0.f, 0.f, 0.f, 0.f);
    if (tmid > 0) {
        issue(xe, fbE, 0, eb0);
        issue(xn, fbN, 0, nb0);
        for (int t = 0; t < tmid; ++t) {
            float4* ecur = (t & 1) ? eb1 : eb0;
            float4* enxt = (t & 1) ? eb0 : eb1;
            float4* ncur = (t & 1) ? nb1 : nb0;
            float4* nnxt = (t & 1) ? nb0 : nb1;
            const bool hn = (t + 1 < tmid);
            if (hn) { issue(xe, fbE, t + 1, enxt); issue(xn, fbN, t + 1, nnxt); }
            // in-order vmcnt: newer-than-tile-t ops =
            //   stores(t-1):4 (t>0) + prefetch loads:8 (hn)
            if (t == 0) { if (hn) WAITV(8);  else WAITV(0); }
            else        { if (hn) WAITV(12); else WAITV(4); }
            float4* op = on + fbN + (size_t)t * TILE_B + w * TILE_W + lane;
            #pragma unroll
            for (int i = 0; i < NCHUNK; ++i) {
                acc4(s, q, ecur[i * CHUNK + lane]);
                nt_store4(op + i * CHUNK, affine4(ncur[i * CHUNK + lane], A0, Bc0));
            }
        }
        WAITV(0);
    }
    // tails: node write remainder, edge stats remainder (plain loads)
    for (int j = tmid * TILE_B + tid; j < fcN; j += 256)
        nt_store4(&on[fbN + j], affine4(xn[fbN + j], A0, Bc0));
    for (int j = tmid * TILE_B + tid; j < fcE; j += 256)
        acc4(s, q, xe[fbE + j]);

    // ---------------- reduce -> A1/Bc1 (edge) -----------------------------
    __syncthreads();                         // redS free for reuse
    redS[tid] = s; redQ[tid] = q;
    __syncthreads();
    if (tid < 32) {
        float4 S = redS[tid], Q = redQ[tid];
        #pragma unroll
        for (int k = 1; k < 8; ++k) {
            const float4 a = redS[k * 32 + tid], c = redQ[k * 32 + tid];
            S.x += a.x; S.y += a.y; S.z += a.z; S.w += a.w;
            Q.x += c.x; Q.y += c.y; Q.z += c.z; Q.w += c.w;
        }
        const float rc = 1.0f / (float)max(cntE, 1);
        float4 m, iv;
        m.x = S.x * rc; m.y = S.y * rc; m.z = S.z * rc; m.w = S.w * rc;
        iv.x = 1.0f / (sqrtf(fmaxf(Q.x * rc - m.x * m.x, 0.f)) + EPS);
        iv.y = 1.0f / (sqrtf(fmaxf(Q.y * rc - m.y * m.y, 0.f)) + EPS);
        iv.z = 1.0f / (sqrtf(fmaxf(Q.z * rc - m.z * m.z, 0.f)) + EPS);
        iv.w = 1.0f / (sqrtf(fmaxf(Q.w * rc - m.w * m.w, 0.f)) + EPS);
        if (cntE <= 1) { m = make_float4(0,0,0,0); iv = make_float4(1,1,1,1); }
        const float4 g4 = ((const float4*)ge)[tid];
        const float4 b4 = ((const float4*)be)[tid];
        float4 A, Bc;
        A.x = iv.x * g4.x; A.y = iv.y * g4.y; A.z = iv.z * g4.z; A.w = iv.w * g4.w;
        Bc.x = b4.x - m.x * A.x; Bc.y = b4.y - m.y * A.y;
        Bc.z = b4.z - m.z * A.z; Bc.w = b4.w - m.w * A.w;
        redS[tid] = A; redQ[tid] = Bc;
    }
    __syncthreads();
    const float4 A1  = redS[dg];
    const float4 Bc1 = redQ[dg];

    // ---------------- P3: edge write (L2/L3 staged re-read) ---------------
    if (ntE > 0) {
        issue(xe, fbE, 0, eb0);
        for (int t = 0; t < ntE; ++t) {
            float4* cur = (t & 1) ? eb1 : eb0;
            float4* nxt = (t & 1) ? eb0 : eb1;
            const bool hn = (t + 1 < ntE);
            if (hn) issue(xe, fbE, t + 1, nxt);
            if (t == 0) { if (hn) WAITV(4); else WAITV(0); }
            else        { if (hn) WAITV(8); else WAITV(4); }
            float4* op = oe + fbE + (size_t)t * TILE_B + w * TILE_W + lane;
            #pragma unroll
            for (int i = 0; i < NCHUNK; ++i)
                nt_store4(op + i * CHUNK, affine4(cur[i * CHUNK + lane], A1, Bc1));
        }
    }
    for (int j = ntE * TILE_B + tid; j < fcE; j += 256)
        nt_store4(&oe[fbE + j], affine4(xe[fbE + j], A1, Bc1));
}

extern "C" void kernel_launch(void* const* d_in, const int* in_sizes, int n_in,
                              void* d_out, int out_size, void* d_ws, size_t ws_size,
                              hipStream_t stream) {
    const float* node_feat  = (const float*)d_in[0];
    const float* edge_feat  = (const float*)d_in[1];
    const float* node_gamma = (const float*)d_in[2];
    const float* node_beta  = (const float*)d_in[3];
    const float* edge_gamma = (const float*)d_in[4];
    const float* edge_beta  = (const float*)d_in[5];
    const int*   node_seg   = (const int*)d_in[6];
    const int*   edge_seg   = (const int*)d_in[7];

    const int D = in_sizes[2];        // 128
    const int N = in_sizes[0] / D;    // 1,000,000
    const int B = 1024;               // num_graphs (fixed by setup_inputs)

    float* out_node = (float*)d_out;
    float* out_edge = out_node + (size_t)N * (size_t)D;

    seg_norm_fused<<<dim3((unsigned)B), 256, 0, stream>>>(
        (const float4*)node_feat, (const float4*)edge_feat,
        node_gamma, node_beta, edge_gamma, edge_beta,
        node_seg, edge_seg,
        (float4*)out_node, (float4*)out_edge, N);
}

// Round 8
// 489.411 us; speedup vs baseline: 1.3168x; 1.1359x over previous
//
#include <hip/hip_runtime.h>

// GraphNormalization on MI355X — R8: 4-deep async global_load_lds pipeline.
//
// Established: traffic minimal (FETCH 1.03GB = read-once, WRITE 1.03GB;
// per-segment re-read fully cache-absorbed). Rate pinned ~3.3-3.4 TB/s in
// R0-R7 — but every variant held only ~1 tile (4KB) in flight per wave
// (~32-40KB/CU). LN/RMSNorm references hit 82-86% BW, so the cap is ours.
// R8: DEPTH=4 tile ring per wave -> 12-16KB in flight per wave, ~96-128KB/CU
// (3-4x all prior rounds). Store-aware counted vmcnt in pass B.

static constexpr int   D4     = 32;              // D/4, D = 128
static constexpr int   CHUNK  = 64;              // f4 per staging inst (1KB/wave)
static constexpr int   NCHUNK = 4;               // insts per wave-tile
static constexpr int   TILE_W = CHUNK * NCHUNK;  // 256 f4 = 4KB per wave
static constexpr int   TILE_B = TILE_W * 4;      // 1024 f4 per block-tile
static constexpr int   DEPTH  = 4;               // tiles in flight per wave
static constexpr float EPS    = 1e-5f;

typedef float vfloat4 __attribute__((ext_vector_type(4)));

#define WAITV(N) do { asm volatile("s_waitcnt vmcnt(" #N ")" ::: "memory"); \
                      __builtin_amdgcn_sched_barrier(0); } while (0)

// wave-uniform runtime wait count (multiples of 4, 0..24)
__device__ __forceinline__ void waitv_dyn(int n) {
    switch (n) {
        case 0:  WAITV(0);  break;
        case 4:  WAITV(4);  break;
        case 8:  WAITV(8);  break;
        case 12: WAITV(12); break;
        case 16: WAITV(16); break;
        case 20: WAITV(20); break;
        default: WAITV(24); break;
    }
}

__device__ __forceinline__ void nt_store4(float4* p, const float4& v) {
    vfloat4 w = { v.x, v.y, v.z, v.w };
    __builtin_nontemporal_store(w, reinterpret_cast<vfloat4*>(p));
}

__device__ __forceinline__ void acc4(float4& s, float4& q, const float4& v) {
    s.x += v.x; s.y += v.y; s.z += v.z; s.w += v.w;
    q.x += v.x * v.x; q.y += v.y * v.y;
    q.z += v.z * v.z; q.w += v.w * v.w;
}

__device__ __forceinline__ float4 affine4(const float4& v, const float4& A,
                                          const float4& Bc) {
    float4 o;
    o.x = v.x * A.x + Bc.x; o.y = v.y * A.y + Bc.y;
    o.z = v.z * A.z + Bc.z; o.w = v.w * A.w + Bc.w;
    return o;
}

__global__ __launch_bounds__(256) void seg_norm_deep(
    const float4* __restrict__ xn, const float4* __restrict__ xe,
    const float*  __restrict__ gn, const float*  __restrict__ bn,
    const float*  __restrict__ ge, const float*  __restrict__ be,
    const int*    __restrict__ sn, const int*    __restrict__ se,
    float4* __restrict__ on, float4* __restrict__ oe,
    int N)
{
    __shared__ float4 stage[4][DEPTH][TILE_W];  // 64 KB: wave-private rings
    __shared__ float4 redS[256], redQ[256];     // 8 KB
    __shared__ int    s_bounds[2];

    const bool is_edge = (blockIdx.y != 0);
    const float4* __restrict__ x   = is_edge ? xe : xn;
    const float*  __restrict__ gam = is_edge ? ge : gn;
    const float*  __restrict__ bet = is_edge ? be : bn;
    const int*    __restrict__ seg = is_edge ? se : sn;
    float4*       __restrict__ out = is_edge ? oe : on;

    const int b   = (int)blockIdx.x;
    const int tid = (int)threadIdx.x;

    if (tid < 2) {
        const int target = b + tid;
        int lo = 0, hi = N;
        while (lo < hi) {
            int mid = (lo + hi) >> 1;
            if (seg[mid] < target) lo = mid + 1; else hi = mid;
        }
        s_bounds[tid] = lo;
    }
    __syncthreads();
    const int start = s_bounds[0];
    const int end   = s_bounds[1];
    const int cnt   = end - start;
    if (cnt <= 0) return;

    const int w    = tid >> 6;    // wave 0..3
    const int lane = tid & 63;
    const int dg   = tid & 31;    // dim-group

    const size_t f4base = (size_t)start * D4;
    const int    f4cnt  = cnt * D4;
    const int    nt     = f4cnt / TILE_B;

    auto issue = [&](int t, float4* lp) {
        const float4* gp = x + f4base + (size_t)t * TILE_B + w * TILE_W + lane;
        #pragma unroll
        for (int i = 0; i < NCHUNK; ++i)
            __builtin_amdgcn_global_load_lds(gp + i * CHUNK, lp + i * CHUNK, 16, 0, 0);
    };

    // ---------------- pass A: stats, DEPTH-deep pipeline -------------------
    float4 s = make_float4(0.f, 0.f, 0.f, 0.f);
    float4 q = make_float4(0.f, 0.f, 0.f, 0.f);
    if (nt > 0) {
        const int pre = min(nt, DEPTH);
        for (int p = 0; p < pre; ++p) issue(p, &stage[w][p][0]);
        for (int t = 0; t < nt; ++t) {
            // newer-than-tile-t loads in flight: 4*min(DEPTH-1, nt-1-t)
            waitv_dyn(4 * min(3, nt - 1 - t));
            float4* cur = &stage[w][t & (DEPTH - 1)][0];
            #pragma unroll
            for (int i = 0; i < NCHUNK; ++i)
                acc4(s, q, cur[i * CHUNK + lane]);
            if (t + DEPTH < nt) issue(t + DEPTH, cur);
        }
    }
    for (int j = nt * TILE_B + tid; j < f4cnt; j += 256)
        acc4(s, q, x[f4base + j]);

    redS[tid] = s; redQ[tid] = q;
    __syncthreads();

    // ---------------- reduce + fold gamma/beta/mean/rstd -------------------
    if (tid < 32) {
        float4 S = redS[tid], Q = redQ[tid];
        #pragma unroll
        for (int k = 1; k < 8; ++k) {
            const float4 a = redS[k * 32 + tid], c = redQ[k * 32 + tid];
            S.x += a.x; S.y += a.y; S.z += a.z; S.w += a.w;
            Q.x += c.x; Q.y += c.y; Q.z += c.z; Q.w += c.w;
        }
        const float rc = 1.0f / (float)cnt;
        float4 m, iv;
        m.x = S.x * rc; m.y = S.y * rc; m.z = S.z * rc; m.w = S.w * rc;
        iv.x = 1.0f / (sqrtf(fmaxf(Q.x * rc - m.x * m.x, 0.f)) + EPS);
        iv.y = 1.0f / (sqrtf(fmaxf(Q.y * rc - m.y * m.y, 0.f)) + EPS);
        iv.z = 1.0f / (sqrtf(fmaxf(Q.z * rc - m.z * m.z, 0.f)) + EPS);
        iv.w = 1.0f / (sqrtf(fmaxf(Q.w * rc - m.w * m.w, 0.f)) + EPS);
        if (cnt <= 1) {  // pass-through: out = x*gamma + beta
            m = make_float4(0.f, 0.f, 0.f, 0.f);
            iv = make_float4(1.f, 1.f, 1.f, 1.f);
        }
        const float4 g4 = ((const float4*)gam)[tid];
        const float4 b4 = ((const float4*)bet)[tid];
        float4 A, Bc;
        A.x = iv.x * g4.x; A.y = iv.y * g4.y; A.z = iv.z * g4.z; A.w = iv.w * g4.w;
        Bc.x = b4.x - m.x * A.x; Bc.y = b4.y - m.y * A.y;
        Bc.z = b4.z - m.z * A.z; Bc.w = b4.w - m.w * A.w;
        redS[tid] = A; redQ[tid] = Bc;   // same-wave lanes only: safe
    }
    __syncthreads();
    const float4 A  = redS[dg];
    const float4 Bc = redQ[dg];
    __syncthreads();   // everyone holds A/Bc before stage reuse

    // ------- pass B: staged re-read (L2/L3) -> fma -> NT store, 4-deep ----
    if (nt > 0) {
        const int pre = min(nt, DEPTH);
        for (int p = 0; p < pre; ++p) issue(p, &stage[w][p][0]);
        for (int t = 0; t < nt; ++t) {
            // newer-than-tile-t VMEM ops: loads 4*min(3,nt-1-t) + stores 4*min(3,t)
            waitv_dyn(4 * min(3, nt - 1 - t) + 4 * min(3, t));
            float4* cur = &stage[w][t & (DEPTH - 1)][0];
            float4* op  = out + f4base + (size_t)t * TILE_B + w * TILE_W + lane;
            #pragma unroll
            for (int i = 0; i < NCHUNK; ++i)
                nt_store4(op + i * CHUNK, affine4(cur[i * CHUNK + lane], A, Bc));
            if (t + DEPTH < nt) issue(t + DEPTH, cur);
        }
    }
    for (int j = nt * TILE_B + tid; j < f4cnt; j += 256)
        nt_store4(&out[f4base + j], affine4(x[f4base + j], A, Bc));
}

extern "C" void kernel_launch(void* const* d_in, const int* in_sizes, int n_in,
                              void* d_out, int out_size, void* d_ws, size_t ws_size,
                              hipStream_t stream) {
    const float* node_feat  = (const float*)d_in[0];
    const float* edge_feat  = (const float*)d_in[1];
    const float* node_gamma = (const float*)d_in[2];
    const float* node_beta  = (const float*)d_in[3];
    const float* edge_gamma = (const float*)d_in[4];
    const float* edge_beta  = (const float*)d_in[5];
    const int*   node_seg   = (const int*)d_in[6];
    const int*   edge_seg   = (const int*)d_in[7];

    const int D = in_sizes[2];        // 128
    const int N = in_sizes[0] / D;    // 1,000,000
    const int B = 1024;               // num_graphs (fixed by setup_inputs)

    float* out_node = (float*)d_out;
    float* out_edge = out_node + (size_t)N * (size_t)D;

    dim3 grid((unsigned)B, 2);
    seg_norm_deep<<<grid, 256, 0, stream>>>(
        (const float4*)node_feat, (const float4*)edge_feat,
        node_gamma, node_beta, edge_gamma, edge_beta,
        node_seg, edge_seg,
        (float4*)out_node, (float4*)out_edge, N);
}